// Round 6
// baseline (19433.292 us; speedup 1.0000x reference)
//
#include <hip/hip_runtime.h>

// Problem constants (match reference)
namespace {
constexpr int B = 16, N = 256, L = 4, H = 128, V = 512, OV = 1000, MAX_STEPS = 48;
constexpr int Z = 4 * H;     // 512 gate width
constexpr int BN = B * N;    // 4096 rows
constexpr int NSL = 16;      // hidden-col slices (8 cols each)
constexpr int RSTR = 132;    // LDS A-stage row stride in u32 (16B aligned, spread banks)
}

typedef __attribute__((ext_vector_type(8))) short short8;  // 8 bf16
typedef __attribute__((ext_vector_type(4))) float f32x4;   // MFMA C/D

union F8 { short8 s; uint4 u; };

__device__ __forceinline__ float sigf(float x) { return 1.0f / (1.0f + __expf(-x)); }
__device__ __forceinline__ float tanh_f(float x) { return 1.0f - 2.0f / (__expf(2.0f * x) + 1.0f); }
__device__ __forceinline__ unsigned short bf16_rne(float x) {
    unsigned u = __float_as_uint(x);
    return (unsigned short)((u + 0x7fffu + ((u >> 16) & 1u)) >> 16);
}
__device__ __forceinline__ unsigned packh(float x) {
    unsigned short hi = bf16_rne(x);
    float hf = __uint_as_float(((unsigned)hi) << 16);
    unsigned short lo = bf16_rne(x - hf);
    return (((unsigned)hi) << 16) | (unsigned)lo;
}
__device__ __forceinline__ float unpackh(unsigned u) {
    return __uint_as_float(u & 0xffff0000u) + __uint_as_float(u << 16);
}

#define AG __HIP_MEMORY_SCOPE_AGENT
__device__ __forceinline__ unsigned ald(const unsigned* p) {
    return __hip_atomic_load((unsigned*)p, __ATOMIC_RELAXED, AG);
}
__device__ __forceinline__ void ast(unsigned* p, unsigned v) {
    __hip_atomic_store(p, v, __ATOMIC_RELAXED, AG);
}

// ---------------------------------------------------------------------------
// tokz[v,:] = emb[v,:] @ Wi0 + b0  (512x512, K=128) fp32, once.
// ---------------------------------------------------------------------------
__global__ __launch_bounds__(256) void k_tokz(const float* __restrict__ emb,
                                              const float* __restrict__ Wi0,
                                              const float* __restrict__ b0,
                                              float* __restrict__ tokz) {
    __shared__ float lds_a[16 * 128];
    float4* l4 = (float4*)lds_a;
    const int tid = threadIdx.x;
    const int c = tid & 127, rg = tid >> 7;
    const int row0 = blockIdx.x * 16;
    {
        const float4* a4 = (const float4*)emb;
        l4[tid] = a4[row0 * 32 + tid];
        l4[tid + 256] = a4[row0 * 32 + tid + 256];
    }
    __syncthreads();
    float acc[8][4];
    {
        float bq[4];
#pragma unroll
        for (int q = 0; q < 4; q++) bq[q] = b0[c + q * 128];
#pragma unroll
        for (int i = 0; i < 8; i++)
#pragma unroll
            for (int q = 0; q < 4; q++) acc[i][q] = bq[q];
    }
    for (int k4 = 0; k4 < 32; k4++) {
        float4 a[8];
#pragma unroll
        for (int i = 0; i < 8; i++) a[i] = l4[(rg * 8 + i) * 32 + k4];
#pragma unroll
        for (int j = 0; j < 4; j++) {
            const int k = k4 * 4 + j;
            const float* wr = Wi0 + k * Z + c;
            const float w0 = wr[0], w1 = wr[128], w2 = wr[256], w3 = wr[384];
#pragma unroll
            for (int i = 0; i < 8; i++) {
                const float av = (j == 0) ? a[i].x : (j == 1) ? a[i].y : (j == 2) ? a[i].z : a[i].w;
                acc[i][0] += av * w0;
                acc[i][1] += av * w1;
                acc[i][2] += av * w2;
                acc[i][3] += av * w3;
            }
        }
    }
#pragma unroll
    for (int i = 0; i < 8; i++) {
        const int row = row0 + rg * 8 + i;
#pragma unroll
        for (int q = 0; q < 4; q++) tokz[row * Z + c + q * 128] = acc[i][q];
    }
}

// ---------------------------------------------------------------------------
// Pack weights per col-slice into MFMA B fragments, bf16 hi/lo.
// Entry e = ((mat*2+ct)*4+ks)*2+split. Lane lp elem j holds
//   W[k][col], k = ks*32 + ((j&4)?16:0) + (lp>>4)*4 + (j&3),
//   col = (ct*2 + ((lp>>3)&1))*128 + slice*8 + (lp&7).
// A uses the same (g,j)->k formula, so true HW k-order cancels.
// ---------------------------------------------------------------------------
__global__ __launch_bounds__(256) void k_pack(const float* __restrict__ Wh0,
                                              const float* __restrict__ Wi1,
                                              const float* __restrict__ Wh1,
                                              unsigned short* __restrict__ wp) {
    const int gid = blockIdx.x * 256 + threadIdx.x;  // 192*256 = 49152
    const int lp = gid & 63;
    const int t2 = gid >> 6;
    const int e = t2 % 48;
    const int slice = t2 / 48;
    const int split = e & 1, ks = (e >> 1) & 3, ct = (e >> 3) & 1, mat = e >> 4;
    const float* W = (mat == 0) ? Wh0 : (mat == 1) ? Wi1 : Wh1;
    const int g = lp >> 4;
    const int col = (ct * 2 + ((lp >> 3) & 1)) * 128 + slice * 8 + (lp & 7);
    unsigned short* dst = wp + ((size_t)slice * 48 + e) * 512 + lp * 8;
#pragma unroll
    for (int j = 0; j < 8; j++) {
        const int k = ks * 32 + ((j & 4) ? 16 : 0) + g * 4 + (j & 3);
        const float x = W[k * Z + col];
        const unsigned short hi = bf16_rne(x);
        unsigned short v = hi;
        if (split) {
            const float hf = __uint_as_float(((unsigned)hi) << 16);
            v = bf16_rne(x - hf);
        }
        dst[j] = v;
    }
}

// ---------------------------------------------------------------------------
// Static per-example CSR (runs once).
// ---------------------------------------------------------------------------
__global__ __launch_bounds__(256) void k_csr(const int* __restrict__ tix,
                                             const int* __restrict__ fix,
                                             int* __restrict__ off,
                                             int* __restrict__ ent) {
    const int b = blockIdx.x;
    const int m = threadIdx.x;
    __shared__ int cnt[N];
    __shared__ int wsum[4];
    cnt[m] = 0;
    __syncthreads();
    const int ti = tix[b * N + m];
    const int fi = fix[b * N + m];
    atomicAdd(&cnt[ti], 1);
    atomicAdd(&cnt[fi], 1);
    __syncthreads();
    const int v = cnt[m];
    const int lane = m & 63, w = m >> 6;
    int sc = v;
#pragma unroll
    for (int o = 1; o < 64; o <<= 1) {
        const int t = __shfl_up(sc, o);
        if (lane >= o) sc += t;
    }
    if (lane == 63) wsum[w] = sc;
    __syncthreads();
    int add = 0;
    for (int i = 0; i < w; i++) add += wsum[i];
    const int base = sc - v + add;
    off[b * (N + 1) + m] = base;
    if (m == N - 1) off[b * (N + 1) + N] = base + v;
    __syncthreads();
    cnt[m] = base;
    __syncthreads();
    const int p1 = atomicAdd(&cnt[ti], 1);
    ent[b * 2 * N + p1] = (m << 1);
    const int p2 = atomicAdd(&cnt[fi], 1);
    ent[b * 2 * N + p2] = (m << 1) | 1;
}

// ---------------------------------------------------------------------------
// zero hcur (1,048,576 u32 as 262,144 uint4) + barcnt
// ---------------------------------------------------------------------------
__global__ __launch_bounds__(256) void k_init(uint4* __restrict__ hcur4,
                                              unsigned* __restrict__ barcnt) {
    const int idx = blockIdx.x * 256 + threadIdx.x;
    hcur4[idx] = make_uint4(0, 0, 0, 0);
    if (blockIdx.x == 0) barcnt[threadIdx.x] = 0;
}

// ---------------------------------------------------------------------------
// Persistent col-sliced kernel. 256 blocks x 512 threads; block bx:
// example b = bx&15, slice = bx>>4 (8 hidden cols). Weights in LDS for all
// steps. Cross-block h exchange via sc1 (agent-scope relaxed atomic) u32
// (bf16 hi|lo). Cluster barrier = 16 blocks of one example, atomic counter.
// ---------------------------------------------------------------------------
__global__ __launch_bounds__(512) void k_persist(
    const unsigned short* __restrict__ wp, const float* __restrict__ b1,
    const float* __restrict__ tokz, const int* __restrict__ data,
    const float* __restrict__ bw, const float* __restrict__ bb,
    unsigned* __restrict__ hw,     // [2 layer][2 par][B][256][128]
    unsigned* __restrict__ hcur,   // [2 layer][B][256][128]
    unsigned* __restrict__ Lbuf,   // [B][NSL][256][2] float bits
    unsigned* __restrict__ barcnt, // [B*16]
    const int* __restrict__ csr_off, const int* __restrict__ csr_ent,
    const int* __restrict__ start, const int* __restrict__ exiti,
    const int* __restrict__ steps) {
    const int bx = blockIdx.x;
    const int b = bx & 15, slice = bx >> 4;
    const int tid = threadIdx.x;
    const int w = tid >> 6, l = tid & 63;
    const int g = l >> 4, li = l & 15;
    const int colg = li & 7;
    const int hcol = slice * 8 + colg;

    __shared__ unsigned short wlds[48 * 512];  // 48KB
    __shared__ unsigned upool[8 * 16 * RSTR];  // 66KB (A-stage / cstage union)
    __shared__ float wtwf[256][2];
    __shared__ float ipl[256];

    unsigned(*aw)[RSTR] = (unsigned(*)[RSTR])(upool + w * 16 * RSTR);
    float* cst = (float*)upool;  // [2][256][9]

    {  // weights -> LDS
        const uint4* src = (const uint4*)(wp + (size_t)slice * 48 * 512);
        uint4* dst = (uint4*)wlds;
        for (int i = tid; i < 48 * 512 / 8; i += 512) dst[i] = src[i];
    }
    {
        const int st = start[b];
        for (int n = tid; n < 256; n += 512) ipl[n] = (n == st) ? 1.0f : 0.0f;
    }

    const int mysteps = steps[b];
    const int ex = exiti[b];
    const int q0 = li >> 3;
    const int gc0 = q0 * 128 + hcol;
    const int gc1 = (2 + q0) * 128 + hcol;
    const float b1A = b1[gc0], b1B = b1[gc1];
    float bwv[4][2];
#pragma unroll
    for (int x = 0; x < 4; x++) {
        bwv[x][0] = bw[(x * 128 + hcol) * 2];
        bwv[x][1] = bw[(x * 128 + hcol) * 2 + 1];
    }
    // which of my 8 (ck,i) slots is the exit row?
    int exslot = -1;
    if (((ex >> 4) & 7) == w && ((ex >> 2) & 3) == g) exslot = ((ex >> 7) & 1) * 4 + (ex & 3);

    const size_t EB = (size_t)256 * 128;
    unsigned* hw00 = hw + ((size_t)(0 * 16 + b)) * EB;
    unsigned* hw01 = hw + ((size_t)(1 * 16 + b)) * EB;
    unsigned* hw10 = hw + ((size_t)(2 * 16 + b)) * EB;
    unsigned* hw11 = hw + ((size_t)(3 * 16 + b)) * EB;
    unsigned* hc0 = hcur + ((size_t)(0 * 16 + b)) * EB;
    unsigned* hc1 = hcur + ((size_t)(1 * 16 + b)) * EB;
    unsigned* bcnt = barcnt + b * 16;

    int ph = 0;
    auto cbar = [&]() {
        asm volatile("s_waitcnt vmcnt(0) lgkmcnt(0)" ::: "memory");
        __syncthreads();
        ph++;
        if (tid == 0) {
            __hip_atomic_fetch_add(bcnt, 1u, __ATOMIC_RELEASE, AG);
            while ((int)__hip_atomic_load(bcnt, __ATOMIC_ACQUIRE, AG) < NSL * ph)
                __builtin_amdgcn_s_sleep(8);
        }
        __syncthreads();
    };

    // wave-private stage of 16 rows x 128 cols of packed h into aw
    auto stage_load = [&](const unsigned* src, int ck, unsigned* v) {
        const int r = l >> 2, cq = (l & 3) * 32;
        const unsigned* s = src + (size_t)(ck * 128 + w * 16 + r) * 128 + cq;
#pragma unroll
        for (int j = 0; j < 32; j++) v[j] = ald(s + j);
    };
    auto stage_store = [&](const unsigned* v) {
        const int r = l >> 2, cq = (l & 3) * 32;
#pragma unroll
        for (int jj = 0; jj < 8; jj++)
            *(uint4*)&aw[r][cq + 4 * jj] =
                make_uint4(v[4 * jj], v[4 * jj + 1], v[4 * jj + 2], v[4 * jj + 3]);
    };
    auto stage = [&](const unsigned* src, int ck) {
        unsigned v[32];
        stage_load(src, ck, v);
        stage_store(v);
    };
    // 3-split bf16 MFMA of staged A vs LDS weights of mat -> accA(ct0), accB(ct1)
    auto gemm3 = [&](f32x4& A0, f32x4& A1, int mat) {
#pragma unroll
        for (int ks = 0; ks < 4; ks++) {
            const unsigned* ar = &aw[li][ks * 32 + g * 4];
            uint4 ua = *(const uint4*)ar;
            uint4 ub = *(const uint4*)(ar + 16);
            unsigned uu[8] = {ua.x, ua.y, ua.z, ua.w, ub.x, ub.y, ub.z, ub.w};
            F8 ah, al2;
#pragma unroll
            for (int j = 0; j < 8; j++) {
                ah.s[j] = (short)(uu[j] >> 16);
                al2.s[j] = (short)(uu[j]);
            }
#pragma unroll
            for (int ct = 0; ct < 2; ct++) {
                const int eb = ((mat * 2 + ct) * 4 + ks) * 2;
                F8 bh, bl;
                bh.u = *(const uint4*)(wlds + eb * 512 + l * 8);
                bl.u = *(const uint4*)(wlds + (eb + 1) * 512 + l * 8);
                f32x4 acc = ct ? A1 : A0;
                acc = __builtin_amdgcn_mfma_f32_16x16x32_bf16(ah.s, bh.s, acc, 0, 0, 0);
                acc = __builtin_amdgcn_mfma_f32_16x16x32_bf16(ah.s, bl.s, acc, 0, 0, 0);
                acc = __builtin_amdgcn_mfma_f32_16x16x32_bf16(al2.s, bh.s, acc, 0, 0, 0);
                if (ct) A1 = acc; else A0 = acc;
            }
        }
    };

    __syncthreads();

    float c0[8] = {}, c1[8] = {}, h0f[8], h1f[8];

    for (int s = 0; s < mysteps; s++) {
        float esc0 = 0.f, esc1 = 0.f;
        if (exslot >= 0 && li < 8) { esc0 = c0[exslot]; esc1 = c1[exslot]; }

#pragma unroll 1
        for (int t = 0; t < L; t++) {
            const unsigned* s0 = (t == 0) ? hc0 : ((t & 1) ? hw01 : hw00);
            unsigned* d0 = ((t + 1) & 1) ? hw01 : hw00;
            // ----- layer 0 -----
#pragma unroll
            for (int ck = 0; ck < 2; ck++) {
                stage(s0, ck);
                f32x4 accA, accB;
#pragma unroll
                for (int i = 0; i < 4; i++) {
                    const int row = ck * 128 + w * 16 + g * 4 + i;
                    const int tok = data[(b * 256 + row) * L + t];
                    accA[i] = tokz[tok * Z + gc0];
                    accB[i] = tokz[tok * Z + gc1];
                }
                gemm3(accA, accB, 0);
#pragma unroll
                for (int i = 0; i < 4; i++) {
                    const float vA = accA[i], vB = accB[i];
                    const float vAp = __shfl_xor(vA, 8);
                    const float vBp = __shfl_xor(vB, 8);
                    if (li < 8) {
                        const int slot = ck * 4 + i;
                        const int row = ck * 128 + w * 16 + g * 4 + i;
                        const float cn = sigf(vAp) * c0[slot] + sigf(vA) * tanh_f(vB);
                        c0[slot] = cn;
                        const float hn = sigf(vBp) * tanh_f(cn);
                        if (t == L - 1) h0f[slot] = hn;
                        ast(d0 + row * 128 + hcol, packh(hn));
                    }
                }
            }
            cbar();  // h0(t) visible cluster-wide (also covers h1(t-1))
            // ----- layer 1 -----
            const unsigned* sA = ((t + 1) & 1) ? hw01 : hw00;
            const unsigned* sB = (t == 0) ? hc1 : ((t & 1) ? hw11 : hw10);
            unsigned* d1 = ((t + 1) & 1) ? hw11 : hw10;
#pragma unroll
            for (int ck = 0; ck < 2; ck++) {
                f32x4 accA, accB;
#pragma unroll
                for (int i = 0; i < 4; i++) { accA[i] = b1A; accB[i] = b1B; }
                stage(sA, ck);
                unsigned vB2[32];
                stage_load(sB, ck, vB2);  // issue early: latency hides under gemm3
                gemm3(accA, accB, 1);
                stage_store(vB2);
                gemm3(accA, accB, 2);
#pragma unroll
                for (int i = 0; i < 4; i++) {
                    const float vA = accA[i], vB = accB[i];
                    const float vAp = __shfl_xor(vA, 8);
                    const float vBp = __shfl_xor(vB, 8);
                    if (li < 8) {
                        const int slot = ck * 4 + i;
                        const int row = ck * 128 + w * 16 + g * 4 + i;
                        const float cn = sigf(vAp) * c1[slot] + sigf(vA) * tanh_f(vB);
                        c1[slot] = cn;
                        const float hn = sigf(vBp) * tanh_f(cn);
                        if (t == L - 1) h1f[slot] = hn;
                        ast(d1 + row * 128 + hcol, packh(hn));
                    }
                }
            }
        }

        // ----- epilogue: exit patch + logit partials + c staging -----
        __syncthreads();  // aw -> cst transition
        if (li < 8) {
            if (exslot >= 0) {
                const unsigned u0 = ald(hc0 + ex * 128 + hcol);
                const unsigned u1 = ald(hc1 + ex * 128 + hcol);
                c0[exslot] = esc0;
                c1[exslot] = esc1;
                h0f[exslot] = unpackh(u0);
                h1f[exslot] = unpackh(u1);
                ast(hw00 + ex * 128 + hcol, u0);  // patched work-h for agg sources
                ast(hw10 + ex * 128 + hcol, u1);
            }
            float lp0[8], lp1[8];
#pragma unroll
            for (int k = 0; k < 8; k++) {
                lp0[k] = c0[k] * bwv[0][0] + h0f[k] * bwv[1][0] + c1[k] * bwv[2][0] + h1f[k] * bwv[3][0];
                lp1[k] = c0[k] * bwv[0][1] + h0f[k] * bwv[1][1] + c1[k] * bwv[2][1] + h1f[k] * bwv[3][1];
            }
#pragma unroll
            for (int m = 1; m < 8; m <<= 1)
#pragma unroll
                for (int k = 0; k < 8; k++) {
                    lp0[k] += __shfl_xor(lp0[k], m);
                    lp1[k] += __shfl_xor(lp1[k], m);
                }
            if (li == 0) {
#pragma unroll
                for (int k = 0; k < 8; k++) {
                    const int row = (k >> 2) * 128 + w * 16 + g * 4 + (k & 3);
                    unsigned* dst = Lbuf + (((size_t)b * NSL + slice) * 256 + row) * 2;
                    ast(dst, __float_as_uint(lp0[k]));
                    ast(dst + 1, __float_as_uint(lp1[k]));
                }
            }
#pragma unroll
            for (int k = 0; k < 8; k++) {
                const int row = (k >> 2) * 128 + w * 16 + g * 4 + (k & 3);
                cst[(0 * 256 + row) * 9 + colg] = c0[k];
                cst[(1 * 256 + row) * 9 + colg] = c1[k];
            }
        }
        cbar();  // logit partials + work states visible

        // ----- softmax (each block redundantly; bitwise identical) -----
        if (tid < 256) {
            float l0 = bb[0], l1 = bb[1];
            for (int sl = 0; sl < NSL; sl++) {
                const unsigned* p = Lbuf + (((size_t)b * NSL + sl) * 256 + tid) * 2;
                l0 += __uint_as_float(ald(p));
                l1 += __uint_as_float(ald(p + 1));
            }
            const float mm = fmaxf(l0, l1);
            const float e0 = __expf(l0 - mm), e1 = __expf(l1 - mm);
            const float inv = 1.0f / (e0 + e1);
            const float ipv = ipl[tid];
            wtwf[tid][0] = e0 * inv * ipv;
            wtwf[tid][1] = e1 * inv * ipv;
        }
        __syncthreads();

        // ----- aggregation (dest rows = own slots; CSR gather) -----
        if (li < 8) {
#pragma unroll
            for (int k = 0; k < 8; k++) {
                const int n = (k >> 2) * 128 + w * 16 + g * 4 + (k & 3);
                const int beg = csr_off[b * (N + 1) + n];
                const int end = csr_off[b * (N + 1) + n + 1];
                float ac0 = 0, ac1 = 0, ah0 = 0, ah1 = 0, ipacc = 0;
                for (int e2 = beg; e2 < end; e2++) {
                    const int pe = csr_ent[b * 2 * N + e2];
                    const int m = pe >> 1;
                    const float wgt = wtwf[m][pe & 1];
                    ipacc += wgt;
                    ac0 += cst[(0 * 256 + m) * 9 + colg] * wgt;
                    ac1 += cst[(1 * 256 + m) * 9 + colg] * wgt;
                    ah0 += unpackh(ald(hw00 + m * 128 + hcol)) * wgt;
                    ah1 += unpackh(ald(hw10 + m * 128 + hcol)) * wgt;
                }
                const float dn = 1.0f / (ipacc + 1e-7f);
                c0[k] = ac0 * dn;
                c1[k] = ac1 * dn;
                ast(hc0 + n * 128 + hcol, packh(ah0 * dn));
                ast(hc1 + n * 128 + hcol, packh(ah1 * dn));
                if (li == 0) ipl[n] = ipacc;
            }
        }
        cbar();  // hcur ready for next step
    }
}

// ---------------------------------------------------------------------------
// out[b,:] = unpack(hcur1[b, exit[b], :]) @ out_w + out_b
// ---------------------------------------------------------------------------
__global__ __launch_bounds__(256) void k_out(const unsigned* __restrict__ hcur,
                                             const float* __restrict__ ow,
                                             const float* __restrict__ ob,
                                             const int* __restrict__ exiti,
                                             float* __restrict__ out) {
    const int b = blockIdx.x;
    __shared__ float h[H];
    const int tid = threadIdx.x;
    if (tid < H) h[tid] = unpackh(hcur[((size_t)(16 + b)) * 256 * 128 + exiti[b] * 128 + tid]);
    __syncthreads();
    for (int v = tid; v < OV; v += 256) {
        float acc = ob[v];
        for (int d = 0; d < H; d++) acc += h[d] * ow[d * OV + v];
        out[b * OV + v] = acc;
    }
}

// ---------------------------------------------------------------------------
extern "C" void kernel_launch(void* const* d_in, const int* in_sizes, int n_in,
                              void* d_out, int out_size, void* d_ws, size_t ws_size,
                              hipStream_t stream) {
    (void)in_sizes; (void)n_in; (void)out_size;
    const int* data = (const int*)d_in[0];
    const int* tix = (const int*)d_in[1];
    const int* fix = (const int*)d_in[2];
    const int* start = (const int*)d_in[3];
    const int* exiti = (const int*)d_in[4];
    const int* steps = (const int*)d_in[5];
    const float* emb = (const float*)d_in[6];
    const float* Wi0 = (const float*)d_in[7];
    const float* Wh0 = (const float*)d_in[8];
    const float* b0 = (const float*)d_in[9];
    const float* Wi1 = (const float*)d_in[10];
    const float* Wh1 = (const float*)d_in[11];
    const float* b1 = (const float*)d_in[12];
    const float* bw = (const float*)d_in[13];
    const float* bb = (const float*)d_in[14];
    const float* ow = (const float*)d_in[15];
    const float* obias = (const float*)d_in[16];
    float* out = (float*)d_out;

    // workspace layout
    float* tokz = (float*)d_ws;                                 // 262144 f32 (1MB)
    unsigned short* wp = (unsigned short*)(tokz + (size_t)V * Z);  // 16*48*512 us (768KB)
    unsigned* hw = (unsigned*)(wp + (size_t)NSL * 48 * 512);    // 2*2*16*32768 u32 (8MB)
    unsigned* hcur = hw + (size_t)4 * 16 * 32768;               // 2*16*32768 u32 (4MB)
    unsigned* Lbuf = hcur + (size_t)2 * 16 * 32768;             // 16*16*256*2 u32 (512KB)
    unsigned* barcnt = Lbuf + (size_t)16 * 16 * 256 * 2;        // 256 u32
    int* csr_off = (int*)(barcnt + 256);                        // 16*257
    int* csr_ent = csr_off + B * (N + 1);                       // 16*512
    const size_t need = (size_t)V * Z * 4 + (size_t)NSL * 48 * 512 * 2 +
                        (size_t)4 * 16 * 32768 * 4 + (size_t)2 * 16 * 32768 * 4 +
                        (size_t)16 * 16 * 256 * 2 * 4 + 256 * 4 +
                        (size_t)(B * (N + 1) + 2 * B * N) * 4;
    if (ws_size < need) return;

    k_tokz<<<V / 16, 256, 0, stream>>>(emb, Wi0, b0, tokz);
    k_pack<<<192, 256, 0, stream>>>(Wh0, Wi1, Wh1, wp);
    k_csr<<<B, 256, 0, stream>>>(tix, fix, csr_off, csr_ent);
    k_init<<<1024, 256, 0, stream>>>((uint4*)hcur, barcnt);

    void* args[] = {(void*)&wp, (void*)&b1, (void*)&tokz, (void*)&data,
                    (void*)&bw, (void*)&bb, (void*)&hw, (void*)&hcur,
                    (void*)&Lbuf, (void*)&barcnt, (void*)&csr_off, (void*)&csr_ent,
                    (void*)&start, (void*)&exiti, (void*)&steps};
    hipLaunchCooperativeKernel((const void*)k_persist, dim3(256), dim3(512),
                               args, 0, stream);

    k_out<<<B, 256, 0, stream>>>(hcur, ow, obias, exiti, out);
}

// Round 7
// 4659.092 us; speedup vs baseline: 4.1710x; 4.1710x over previous
//
#include <hip/hip_runtime.h>

// Problem constants (match reference)
namespace {
constexpr int B = 16, N = 256, L = 4, H = 128, V = 512, OV = 1000, MAX_STEPS = 48;
constexpr int Z = 4 * H;   // 512 gate width
constexpr int BN = B * N;  // 4096 rows
constexpr int PADK = 132;  // padded LDS row stride (ushorts) to break bank aliasing
}

typedef __attribute__((ext_vector_type(8))) short short8;  // 8 bf16 (4 VGPRs)
typedef __attribute__((ext_vector_type(4))) float f32x4;   // MFMA C/D

union F8 {
    short8 s;
    uint4 u;
    uint2 h[2];
};

__device__ __forceinline__ float sigf(float x) { return 1.0f / (1.0f + __expf(-x)); }
__device__ __forceinline__ float tanh_f(float x) { return 1.0f - 2.0f / (__expf(2.0f * x) + 1.0f); }

__device__ __forceinline__ unsigned short bf16_rne(float x) {
    unsigned u = __float_as_uint(x);
    return (unsigned short)((u + 0x7fffu + ((u >> 16) & 1u)) >> 16);
}
__device__ __forceinline__ void split2(float x, unsigned short& hi, unsigned short& lo) {
    hi = bf16_rne(x);
    const float hf = __uint_as_float(((unsigned)hi) << 16);
    lo = bf16_rne(x - hf);
}

// ---------------------------------------------------------------------------
// init: zero the 4 "cur" state tensors + init ip
// ---------------------------------------------------------------------------
__global__ __launch_bounds__(256) void k_init(float4* __restrict__ cur4,
                                              float* __restrict__ ip,
                                              const int* __restrict__ start) {
    const int idx = blockIdx.x * 256 + threadIdx.x;
    cur4[idx] = make_float4(0.f, 0.f, 0.f, 0.f);
    if (idx < BN) ip[idx] = ((idx & (N - 1)) == start[idx >> 8]) ? 1.0f : 0.0f;
}

// ---------------------------------------------------------------------------
// tokz[v, :] = emb[v, :] @ Wi0 + b0   (512 x 512, K=128) -- fp32, computed once.
// ---------------------------------------------------------------------------
__global__ __launch_bounds__(256) void k_tokz(const float* __restrict__ emb,
                                              const float* __restrict__ Wi0,
                                              const float* __restrict__ b0,
                                              float* __restrict__ tokz) {
    __shared__ float lds_a[16 * 128];
    float4* l4 = (float4*)lds_a;
    const int tid = threadIdx.x;
    const int c = tid & 127, rg = tid >> 7;
    const int row0 = blockIdx.x * 16;
    {
        const float4* a4 = (const float4*)emb;
        l4[tid] = a4[row0 * 32 + tid];
        l4[tid + 256] = a4[row0 * 32 + tid + 256];
    }
    __syncthreads();
    float acc[8][4];
    {
        float bq[4];
#pragma unroll
        for (int q = 0; q < 4; q++) bq[q] = b0[c + q * 128];
#pragma unroll
        for (int i = 0; i < 8; i++)
#pragma unroll
            for (int q = 0; q < 4; q++) acc[i][q] = bq[q];
    }
    for (int k4 = 0; k4 < 32; k4++) {
        float4 a[8];
#pragma unroll
        for (int i = 0; i < 8; i++) a[i] = l4[(rg * 8 + i) * 32 + k4];
#pragma unroll
        for (int j = 0; j < 4; j++) {
            const int k = k4 * 4 + j;
            const float* wr = Wi0 + k * Z + c;
            const float w0 = wr[0], w1 = wr[128], w2 = wr[256], w3 = wr[384];
#pragma unroll
            for (int i = 0; i < 8; i++) {
                const float av = (j == 0) ? a[i].x : (j == 1) ? a[i].y : (j == 2) ? a[i].z : a[i].w;
                acc[i][0] += av * w0;
                acc[i][1] += av * w1;
                acc[i][2] += av * w2;
                acc[i][3] += av * w3;
            }
        }
    }
#pragma unroll
    for (int i = 0; i < 8; i++) {
        const int row = row0 + rg * 8 + i;
#pragma unroll
        for (int q = 0; q < 4; q++) tokz[row * Z + c + q * 128] = acc[i][q];
    }
}

// ---------------------------------------------------------------------------
// Pack weights into MFMA B-fragment order, split into bf16 hi/lo.
// Entry (mat,q,w,ks): 64 lanes x 8 bf16; lane lp elem j holds
//   W[k][col],  k = ks*32 + ((j&4)?16:0) + (lp>>4)*4 + (j&3),
//               col = q*128 + w*16 + (lp&15).
// Same (g,j)->k formula is used for A fragments, so the true HW k-order
// cancels (dot over k is permutation-invariant).
// ---------------------------------------------------------------------------
__global__ __launch_bounds__(256) void k_pack(const float* __restrict__ Wh0,
                                              const float* __restrict__ Wi1,
                                              const float* __restrict__ Wh1,
                                              unsigned short* __restrict__ WPhi,
                                              unsigned short* __restrict__ WPlo) {
    const int gid = blockIdx.x * 256 + threadIdx.x;
    const int lp = gid & 63;
    const int ks = (gid >> 6) & 3;
    const int w = (gid >> 8) & 7;
    const int q = (gid >> 11) & 3;
    const int split = (gid >> 13) & 1;
    const int mat = gid >> 14;  // 0..2
    const float* W = (mat == 0) ? Wh0 : (mat == 1) ? Wi1 : Wh1;
    const int g = lp >> 4, li = lp & 15;
    const int col = q * 128 + w * 16 + li;
    const int e = ((mat * 4 + q) * 8 + w) * 4 + ks;
    unsigned short* dst = (split ? WPlo : WPhi) + (size_t)e * 512 + lp * 8;
#pragma unroll
    for (int j = 0; j < 8; j++) {
        const int k = ks * 32 + ((j & 4) ? 16 : 0) + g * 4 + (j & 3);
        const float x = W[k * Z + col];
        const unsigned short hi = bf16_rne(x);
        unsigned short v = hi;
        if (split) {
            const float hf = __uint_as_float(((unsigned)hi) << 16);
            v = bf16_rne(x - hf);
        }
        dst[j] = v;
    }
}

// ---------------------------------------------------------------------------
// Build per-example CSR of dest <- (src, branch-flag). Runs once.
// ---------------------------------------------------------------------------
__global__ __launch_bounds__(256) void k_csr(const int* __restrict__ tix,
                                             const int* __restrict__ fix,
                                             int* __restrict__ off,
                                             int* __restrict__ ent) {
    const int b = blockIdx.x;
    const int m = threadIdx.x;
    __shared__ int cnt[N];
    __shared__ int wsum[4];
    cnt[m] = 0;
    __syncthreads();
    const int ti = tix[b * N + m];
    const int fi = fix[b * N + m];
    atomicAdd(&cnt[ti], 1);
    atomicAdd(&cnt[fi], 1);
    __syncthreads();
    const int v = cnt[m];
    const int lane = m & 63, w = m >> 6;
    int sc = v;
#pragma unroll
    for (int o = 1; o < 64; o <<= 1) {
        const int t = __shfl_up(sc, o);
        if (lane >= o) sc += t;
    }
    if (lane == 63) wsum[w] = sc;
    __syncthreads();
    int add = 0;
    for (int i = 0; i < w; i++) add += wsum[i];
    const int base = sc - v + add;
    off[b * (N + 1) + m] = base;
    if (m == N - 1) off[b * (N + 1) + N] = base + v;
    __syncthreads();
    cnt[m] = base;
    __syncthreads();
    const int p1 = atomicAdd(&cnt[ti], 1);
    ent[b * 2 * N + p1] = (m << 1);
    const int p2 = atomicAdd(&cnt[fi], 1);
    ent[b * 2 * N + p2] = (m << 1) | 1;
}

// ---------------------------------------------------------------------------
// Fused per-step scan, MFMA version, spill-controlled.
// Block = 16 rows, 512 threads = 8 waves. Wave w owns cols {q*128 + w*16 + li}.
// MFMA nests are q-outer with sched_barrier(0) between q-chunks so the
// compiler cannot hoist all fragment loads into one giant live set
// (R3/R4 spilled ~420 KB/block -> 107 MB HBM writes/dispatch).
// ---------------------------------------------------------------------------
__global__ __launch_bounds__(512) void k_scan(
    const float* __restrict__ c0c, const float* __restrict__ h0c,
    const float* __restrict__ c1c, const float* __restrict__ h1c,
    float* __restrict__ c0w, float* __restrict__ h0w,
    float* __restrict__ c1w, float* __restrict__ h1w,
    const unsigned short* __restrict__ WPhi, const unsigned short* __restrict__ WPlo,
    const float* __restrict__ b1,
    const float* __restrict__ tokz, const int* __restrict__ data,
    const float* __restrict__ bw, const float* __restrict__ bb,
    const float* __restrict__ ip, float* __restrict__ wt, float* __restrict__ wf,
    const int* __restrict__ exiti, const int* __restrict__ steps, const int s) {
    const int bx = blockIdx.x;
    const int b = bx >> 4;
    if (s >= steps[b]) return;  // per-example early exit (block-uniform)
    const int row0 = bx * 16;
    const int tid = threadIdx.x;
    const int w = tid >> 6;
    const int l = tid & 63;
    const int g = l >> 4, li = l & 15;
    const int ch = w * 16 + li;  // hidden col 0..127

    __shared__ unsigned short h0hi[16 * PADK], h0lo[16 * PADK];
    __shared__ unsigned short h1hi[16 * PADK], h1lo[16 * PADK];
    __shared__ float red[16][8][2];

    float c0[4], c1[4], h0[4], h1[4];
#pragma unroll
    for (int r = 0; r < 4; r++) {
        const int off = (row0 + g * 4 + r) * H + ch;
        c0[r] = c0c[off];
        h0[r] = h0c[off];
        c1[r] = c1c[off];
        h1[r] = h1c[off];
    }
    float b1v[4];
#pragma unroll
    for (int q = 0; q < 4; q++) b1v[q] = b1[q * 128 + ch];

    // initial h -> LDS (bf16 hi/lo)
#pragma unroll
    for (int r = 0; r < 4; r++) {
        unsigned short hi, lo;
        split2(h0[r], hi, lo);
        h0hi[(g * 4 + r) * PADK + ch] = hi;
        h0lo[(g * 4 + r) * PADK + ch] = lo;
        split2(h1[r], hi, lo);
        h1hi[(g * 4 + r) * PADK + ch] = hi;
        h1lo[(g * 4 + r) * PADK + ch] = lo;
    }
    __syncthreads();

#pragma unroll 1
    for (int t = 0; t < L; t++) {
        f32x4 acc[4];
        // ================= layer 0: z = tokz[data[:,t]] + h0 @ Wh0 ==========
        {
            int tok[4];
#pragma unroll
            for (int r = 0; r < 4; r++) tok[r] = data[(row0 + g * 4 + r) * L + t];
#pragma unroll
            for (int q = 0; q < 4; q++)
#pragma unroll
                for (int r = 0; r < 4; r++) acc[q][r] = tokz[tok[r] * Z + q * 128 + ch];
        }
#pragma unroll
        for (int q = 0; q < 4; q++) {
#pragma unroll
            for (int ks = 0; ks < 4; ks++) {
                F8 ahi, alo;
                const int ab = li * PADK + ks * 32 + g * 4;
                ahi.h[0] = *(const uint2*)&h0hi[ab];
                ahi.h[1] = *(const uint2*)&h0hi[ab + 16];
                alo.h[0] = *(const uint2*)&h0lo[ab];
                alo.h[1] = *(const uint2*)&h0lo[ab + 16];
                F8 bhi, blo;
                const int e = (q * 8 + w) * 4 + ks;
                bhi.u = *(const uint4*)(WPhi + (size_t)e * 512 + l * 8);
                blo.u = *(const uint4*)(WPlo + (size_t)e * 512 + l * 8);
                acc[q] = __builtin_amdgcn_mfma_f32_16x16x32_bf16(ahi.s, bhi.s, acc[q], 0, 0, 0);
                acc[q] = __builtin_amdgcn_mfma_f32_16x16x32_bf16(ahi.s, blo.s, acc[q], 0, 0, 0);
                acc[q] = __builtin_amdgcn_mfma_f32_16x16x32_bf16(alo.s, bhi.s, acc[q], 0, 0, 0);
            }
            __builtin_amdgcn_sched_barrier(0);  // cap live fragment set per q-chunk
        }
#pragma unroll
        for (int r = 0; r < 4; r++) {
            const float cn = sigf(acc[1][r]) * c0[r] + sigf(acc[0][r]) * tanh_f(acc[2][r]);
            c0[r] = cn;
            h0[r] = sigf(acc[3][r]) * tanh_f(cn);
        }
        __syncthreads();  // all waves done reading h0 bufs
#pragma unroll
        for (int r = 0; r < 4; r++) {
            unsigned short hi, lo;
            split2(h0[r], hi, lo);
            h0hi[(g * 4 + r) * PADK + ch] = hi;
            h0lo[(g * 4 + r) * PADK + ch] = lo;
        }
        __syncthreads();
        // ================= layer 1: z = h0new @ Wi1 + h1 @ Wh1 + b1 =========
#pragma unroll
        for (int q = 0; q < 4; q++) {
            const float bv = b1v[q];
            acc[q][0] = bv; acc[q][1] = bv; acc[q][2] = bv; acc[q][3] = bv;
        }
#pragma unroll
        for (int q = 0; q < 4; q++) {
#pragma unroll
            for (int ks = 0; ks < 4; ks++) {
                F8 a0hi, a0lo, a1hi, a1lo;
                const int ab = li * PADK + ks * 32 + g * 4;
                a0hi.h[0] = *(const uint2*)&h0hi[ab];
                a0hi.h[1] = *(const uint2*)&h0hi[ab + 16];
                a0lo.h[0] = *(const uint2*)&h0lo[ab];
                a0lo.h[1] = *(const uint2*)&h0lo[ab + 16];
                a1hi.h[0] = *(const uint2*)&h1hi[ab];
                a1hi.h[1] = *(const uint2*)&h1hi[ab + 16];
                a1lo.h[0] = *(const uint2*)&h1lo[ab];
                a1lo.h[1] = *(const uint2*)&h1lo[ab + 16];
                F8 b1hi, b1lo, b2hi, b2lo;
                const int e1 = ((4 + q) * 8 + w) * 4 + ks;
                const int e2 = ((8 + q) * 8 + w) * 4 + ks;
                b1hi.u = *(const uint4*)(WPhi + (size_t)e1 * 512 + l * 8);
                b1lo.u = *(const uint4*)(WPlo + (size_t)e1 * 512 + l * 8);
                b2hi.u = *(const uint4*)(WPhi + (size_t)e2 * 512 + l * 8);
                b2lo.u = *(const uint4*)(WPlo + (size_t)e2 * 512 + l * 8);
                acc[q] = __builtin_amdgcn_mfma_f32_16x16x32_bf16(a0hi.s, b1hi.s, acc[q], 0, 0, 0);
                acc[q] = __builtin_amdgcn_mfma_f32_16x16x32_bf16(a0hi.s, b1lo.s, acc[q], 0, 0, 0);
                acc[q] = __builtin_amdgcn_mfma_f32_16x16x32_bf16(a0lo.s, b1hi.s, acc[q], 0, 0, 0);
                acc[q] = __builtin_amdgcn_mfma_f32_16x16x32_bf16(a1hi.s, b2hi.s, acc[q], 0, 0, 0);
                acc[q] = __builtin_amdgcn_mfma_f32_16x16x32_bf16(a1hi.s, b2lo.s, acc[q], 0, 0, 0);
                acc[q] = __builtin_amdgcn_mfma_f32_16x16x32_bf16(a1lo.s, b2hi.s, acc[q], 0, 0, 0);
            }
            __builtin_amdgcn_sched_barrier(0);  // cap live fragment set per q-chunk
        }
#pragma unroll
        for (int r = 0; r < 4; r++) {
            const float cn = sigf(acc[1][r]) * c1[r] + sigf(acc[0][r]) * tanh_f(acc[2][r]);
            c1[r] = cn;
            h1[r] = sigf(acc[3][r]) * tanh_f(cn);
        }
        __syncthreads();  // all waves done reading h1 bufs
#pragma unroll
        for (int r = 0; r < 4; r++) {
            unsigned short hi, lo;
            split2(h1[r], hi, lo);
            h1hi[(g * 4 + r) * PADK + ch] = hi;
            h1lo[(g * 4 + r) * PADK + ch] = lo;
        }
        __syncthreads();
    }

    // -------- exit-row patch: contrib[exit] = cur[exit] (block-uniform guard)
    const int ex = exiti[b];
    if ((ex >> 4) == (bx & 15)) {
        const int rl = ex & 15;
#pragma unroll
        for (int r = 0; r < 4; r++) {
            if (g * 4 + r == rl) {
                const int off = (row0 + rl) * H + ch;
                c0[r] = c0c[off];
                h0[r] = h0c[off];
                c1[r] = c1c[off];
                h1[r] = h1c[off];
            }
        }
    }
    // -------- store work states (read by k_agg)
#pragma unroll
    for (int r = 0; r < 4; r++) {
        const int off = (row0 + g * 4 + r) * H + ch;
        c0w[off] = c0[r];
        h0w[off] = h0[r];
        c1w[off] = c1[r];
        h1w[off] = h1[r];
    }
    // -------- branch softmax: l = concat(c0,h0,c1,h1) @ bw + bb, * ip
    float2 bwv[4];
#pragma unroll
    for (int x = 0; x < 4; x++) bwv[x] = ((const float2*)bw)[x * 128 + ch];
    float l0p[4], l1p[4];
#pragma unroll
    for (int r = 0; r < 4; r++) {
        l0p[r] = c0[r] * bwv[0].x + h0[r] * bwv[1].x + c1[r] * bwv[2].x + h1[r] * bwv[3].x;
        l1p[r] = c0[r] * bwv[0].y + h0[r] * bwv[1].y + c1[r] * bwv[2].y + h1[r] * bwv[3].y;
    }
#pragma unroll
    for (int off = 8; off > 0; off >>= 1)
#pragma unroll
        for (int r = 0; r < 4; r++) {
            l0p[r] += __shfl_xor(l0p[r], off);
            l1p[r] += __shfl_xor(l1p[r], off);
        }
    if (li == 0)
#pragma unroll
        for (int r = 0; r < 4; r++) {
            red[g * 4 + r][w][0] = l0p[r];
            red[g * 4 + r][w][1] = l1p[r];
        }
    __syncthreads();
    if (tid < 16) {
        float l0 = bb[0], l1 = bb[1];
#pragma unroll
        for (int ww = 0; ww < 8; ww++) {
            l0 += red[tid][ww][0];
            l1 += red[tid][ww][1];
        }
        const float m = fmaxf(l0, l1);
        const float e0 = __expf(l0 - m), e1 = __expf(l1 - m);
        const float inv = 1.0f / (e0 + e1);
        const float ipv = ip[row0 + tid];
        wt[row0 + tid] = e0 * inv * ipv;
        wf[row0 + tid] = e1 * inv * ipv;
    }
}

// ---------------------------------------------------------------------------
// ip redistribution + weighted state aggregation via static CSR.
// One wave per dest node; block = 4 waves, same example. grid = 1024.
// ---------------------------------------------------------------------------
__global__ __launch_bounds__(256) void k_agg(
    const float* __restrict__ c0w, const float* __restrict__ h0w,
    const float* __restrict__ c1w, const float* __restrict__ h1w,
    float* __restrict__ c0c, float* __restrict__ h0c,
    float* __restrict__ c1c, float* __restrict__ h1c,
    const int* __restrict__ off, const int* __restrict__ ent,
    const float* __restrict__ wt, const float* __restrict__ wf,
    float* __restrict__ ip, const int* __restrict__ steps, const int s) {
    const int row00 = blockIdx.x * 4;
    const int b = row00 >> 8;
    if (s >= steps[b]) return;
    const int tid = threadIdx.x;
    const int lane = tid & 63;
    const int n = (row00 & (N - 1)) + (tid >> 6);
    const int rowb = b * N;
    const int beg = off[b * (N + 1) + n];
    const int end = off[b * (N + 1) + n + 1];
    float a00 = 0, a01 = 0, a10 = 0, a11 = 0, a20 = 0, a21 = 0, a30 = 0, a31 = 0;
    float ipacc = 0.f;
    for (int e = beg; e < end; e++) {
        const int pe = ent[b * 2 * N + e];
        const int m = pe >> 1;
        const float wgt = (pe & 1) ? wf[rowb + m] : wt[rowb + m];
        ipacc += wgt;
        const int rb = (rowb + m) * H;
        a00 += c0w[rb + lane] * wgt;
        a01 += c0w[rb + lane + 64] * wgt;
        a10 += h0w[rb + lane] * wgt;
        a11 += h0w[rb + lane + 64] * wgt;
        a20 += c1w[rb + lane] * wgt;
        a21 += c1w[rb + lane + 64] * wgt;
        a30 += h1w[rb + lane] * wgt;
        a31 += h1w[rb + lane + 64] * wgt;
    }
    const float dn = 1.0f / (ipacc + 1e-7f);
    const int ob = (rowb + n) * H;
    c0c[ob + lane] = a00 * dn;
    c0c[ob + lane + 64] = a01 * dn;
    h0c[ob + lane] = a10 * dn;
    h0c[ob + lane + 64] = a11 * dn;
    c1c[ob + lane] = a20 * dn;
    c1c[ob + lane + 64] = a21 * dn;
    h1c[ob + lane] = a30 * dn;
    h1c[ob + lane + 64] = a31 * dn;
    if (lane == 0) ip[rowb + n] = ipacc;
}

// ---------------------------------------------------------------------------
// out[b, :] = h1_cur[b, exit[b], :] @ out_w + out_b
// ---------------------------------------------------------------------------
__global__ __launch_bounds__(256) void k_out(const float* __restrict__ h1c,
                                             const float* __restrict__ ow,
                                             const float* __restrict__ ob,
                                             const int* __restrict__ exiti,
                                             float* __restrict__ out) {
    const int b = blockIdx.x;
    __shared__ float h[H];
    const int tid = threadIdx.x;
    if (tid < H) h[tid] = h1c[(b * N + exiti[b]) * H + tid];
    __syncthreads();
    for (int v = tid; v < OV; v += 256) {
        float acc = ob[v];
        for (int d = 0; d < H; d++) acc += h[d] * ow[d * OV + v];
        out[b * OV + v] = acc;
    }
}

// ---------------------------------------------------------------------------
extern "C" void kernel_launch(void* const* d_in, const int* in_sizes, int n_in,
                              void* d_out, int out_size, void* d_ws, size_t ws_size,
                              hipStream_t stream) {
    (void)in_sizes; (void)n_in; (void)out_size;
    const int* data = (const int*)d_in[0];
    const int* tix = (const int*)d_in[1];
    const int* fix = (const int*)d_in[2];
    const int* start = (const int*)d_in[3];
    const int* exiti = (const int*)d_in[4];
    const int* steps = (const int*)d_in[5];
    const float* emb = (const float*)d_in[6];
    const float* Wi0 = (const float*)d_in[7];
    const float* Wh0 = (const float*)d_in[8];
    const float* b0 = (const float*)d_in[9];
    const float* Wi1 = (const float*)d_in[10];
    const float* Wh1 = (const float*)d_in[11];
    const float* b1 = (const float*)d_in[12];
    const float* bw = (const float*)d_in[13];
    const float* bb = (const float*)d_in[14];
    const float* ow = (const float*)d_in[15];
    const float* obias = (const float*)d_in[16];
    float* out = (float*)d_out;

    // workspace layout (floats)
    const size_t SB = (size_t)BN * H;  // 524288 per state tensor
    float* ws = (float*)d_ws;
    float* c0c = ws;
    float* h0c = ws + 1 * SB;
    float* c1c = ws + 2 * SB;
    float* h1c = ws + 3 * SB;
    float* c0w = ws + 4 * SB;
    float* h0w = ws + 5 * SB;
    float* c1w = ws + 6 * SB;
    float* h1w = ws + 7 * SB;
    float* tokz = ws + 8 * SB;         // V*Z = 262144
    float* ip = tokz + (size_t)V * Z;  // BN
    float* wt = ip + BN;               // BN
    float* wf = wt + BN;               // BN
    unsigned short* WPhi = (unsigned short*)(wf + BN);  // 3*65536 ushorts
    unsigned short* WPlo = WPhi + 3 * 65536;            // 3*65536 ushorts
    int* csr_off = (int*)(WPlo + 3 * 65536);            // B*(N+1)
    int* csr_ent = csr_off + B * (N + 1);               // B*2N
    const size_t need = (8 * SB + (size_t)V * Z + 3 * (size_t)BN) * sizeof(float) +
                        2 * 3 * 65536 * sizeof(unsigned short) +
                        (B * (N + 1) + B * 2 * N) * sizeof(int);
    if (ws_size < need) return;

    k_init<<<(4 * SB / 4) / 256, 256, 0, stream>>>((float4*)ws, ip, start);
    k_tokz<<<V / 16, 256, 0, stream>>>(emb, Wi0, b0, tokz);
    k_pack<<<192, 256, 0, stream>>>(Wh0, Wi1, Wh1, WPhi, WPlo);
    k_csr<<<B, 256, 0, stream>>>(tix, fix, csr_off, csr_ent);

    for (int s = 0; s < MAX_STEPS; s++) {
        k_scan<<<BN / 16, 512, 0, stream>>>(c0c, h0c, c1c, h1c, c0w, h0w, c1w, h1w,
                                            WPhi, WPlo, b1, tokz, data, bw, bb,
                                            ip, wt, wf, exiti, steps, s);
        k_agg<<<BN / 4, 256, 0, stream>>>(c0w, h0w, c1w, h1w, c0c, h0c, c1c, h1c,
                                          csr_off, csr_ent, wt, wf, ip, steps, s);
    }
    k_out<<<B, 256, 0, stream>>>(h1c, ow, obias, exiti, out);
}